// Round 1
// baseline (8888.420 us; speedup 1.0000x reference)
//
#include <hip/hip_runtime.h>
#include <math.h>

#define NN 50000
#define NE 600000
#define HID 128
#define NCLS 10

// ---------------- graph prep ----------------

__global__ __launch_bounds__(256) void k_init_deg(float* __restrict__ deg) {
    int i = blockIdx.x * 256 + threadIdx.x;
    if (i < NN) deg[i] = 1.0f;  // self-loop contributes 1
}

__global__ __launch_bounds__(256) void k_count_deg(const int* __restrict__ edge,
                                                   float* __restrict__ deg) {
    int e = blockIdx.x * 256 + threadIdx.x;
    if (e < NE) atomicAdd(&deg[edge[NE + e]], 1.0f);  // deg on dst
}

__global__ __launch_bounds__(256) void k_dinv(float* __restrict__ deg) {
    int i = blockIdx.x * 256 + threadIdx.x;
    if (i < NN) deg[i] = rsqrtf(deg[i]);  // deg >= 1 always (self-loop)
}

__global__ __launch_bounds__(256) void k_norm(const int* __restrict__ edge,
                                              const float* __restrict__ dinv,
                                              float* __restrict__ norm) {
    int e = blockIdx.x * 256 + threadIdx.x;
    if (e < NE) norm[e] = dinv[edge[e]] * dinv[edge[NE + e]];
}

// ---------------- dense: H[N,128] @ W[128,128] -> T[N,128] ----------------
// block = 256 threads = 8 row-groups x 32 col-groups; each thread: 4 rows x 4 cols.
// Block covers 32 rows. W rows stream through L1/L2 (64 KB, fully cacheable).

__device__ __forceinline__ float f4_get(const float4& v, int i) {
    return i == 0 ? v.x : i == 1 ? v.y : i == 2 ? v.z : v.w;
}

__global__ __launch_bounds__(256) void k_matmul128(const float* __restrict__ H,
                                                   const float* __restrict__ W,
                                                   float* __restrict__ T) {
    int tid = threadIdx.x;
    int cg  = tid & 31;        // cols 4*cg .. 4*cg+3
    int rg  = tid >> 5;        // 0..7
    int row0 = blockIdx.x * 32 + rg * 4;
    if (row0 >= NN) return;    // NN % 4 == 0 -> per-thread rows all-valid or all-invalid

    const float4* W4 = (const float4*)W;  // W4[k*32 + cg]
    const float4* h0 = (const float4*)(H + (size_t)(row0 + 0) * HID);
    const float4* h1 = (const float4*)(H + (size_t)(row0 + 1) * HID);
    const float4* h2 = (const float4*)(H + (size_t)(row0 + 2) * HID);
    const float4* h3 = (const float4*)(H + (size_t)(row0 + 3) * HID);

    float4 acc0 = {0, 0, 0, 0}, acc1 = {0, 0, 0, 0}, acc2 = {0, 0, 0, 0}, acc3 = {0, 0, 0, 0};

#pragma unroll 8
    for (int k4 = 0; k4 < HID / 4; ++k4) {
        float4 a0 = h0[k4], a1 = h1[k4], a2 = h2[k4], a3 = h3[k4];
#pragma unroll
        for (int kk = 0; kk < 4; ++kk) {
            float4 w = W4[(size_t)(k4 * 4 + kk) * 32 + cg];
            float s0 = f4_get(a0, kk), s1 = f4_get(a1, kk);
            float s2 = f4_get(a2, kk), s3 = f4_get(a3, kk);
            acc0.x += s0 * w.x; acc0.y += s0 * w.y; acc0.z += s0 * w.z; acc0.w += s0 * w.w;
            acc1.x += s1 * w.x; acc1.y += s1 * w.y; acc1.z += s1 * w.z; acc1.w += s1 * w.w;
            acc2.x += s2 * w.x; acc2.y += s2 * w.y; acc2.z += s2 * w.z; acc2.w += s2 * w.w;
            acc3.x += s3 * w.x; acc3.y += s3 * w.y; acc3.z += s3 * w.z; acc3.w += s3 * w.w;
        }
    }
    ((float4*)(T + (size_t)(row0 + 0) * HID))[cg] = acc0;
    ((float4*)(T + (size_t)(row0 + 1) * HID))[cg] = acc1;
    ((float4*)(T + (size_t)(row0 + 2) * HID))[cg] = acc2;
    ((float4*)(T + (size_t)(row0 + 3) * HID))[cg] = acc3;
}

// ---------------- sparse: agg[dst] += T[src] * norm ----------------
// 32 threads per edge, each handles a float4 of the 128-wide feature row.

__global__ __launch_bounds__(256) void k_scatter128(const float* __restrict__ T,
                                                    float* __restrict__ agg,
                                                    const int* __restrict__ edge,
                                                    const float* __restrict__ norm) {
    int gid = blockIdx.x * 256 + threadIdx.x;
    int e = gid >> 5, fg = gid & 31;
    if (e >= NE) return;
    int s = edge[e], d = edge[NE + e];
    float nrm = norm[e];
    float4 v = ((const float4*)(T + (size_t)s * HID))[fg];
    float* o = agg + (size_t)d * HID + fg * 4;
    atomicAdd(o + 0, v.x * nrm);
    atomicAdd(o + 1, v.y * nrm);
    atomicAdd(o + 2, v.z * nrm);
    atomicAdd(o + 3, v.w * nrm);
}

// agg = ELU(agg + dinv^2 * T + b)   (self-loop + bias + activation)
__global__ __launch_bounds__(256) void k_finalize128(float* __restrict__ agg,
                                                     const float* __restrict__ T,
                                                     const float* __restrict__ dinv,
                                                     const float* __restrict__ bias,
                                                     int do_elu) {
    int gid = blockIdx.x * 256 + threadIdx.x;  // NN*32 threads
    int row = gid >> 5, fg = gid & 31;
    if (row >= NN) return;
    float sn = dinv[row];
    sn *= sn;
    float4 a = ((const float4*)agg)[gid];
    float4 t = ((const float4*)T)[gid];
    float4 b = ((const float4*)bias)[fg];
    float4 r;
    r.x = a.x + sn * t.x + b.x;
    r.y = a.y + sn * t.y + b.y;
    r.z = a.z + sn * t.z + b.z;
    r.w = a.w + sn * t.w + b.w;
    if (do_elu) {
        r.x = r.x > 0.f ? r.x : expm1f(r.x);
        r.y = r.y > 0.f ? r.y : expm1f(r.y);
        r.z = r.z > 0.f ? r.z : expm1f(r.z);
        r.w = r.w > 0.f ? r.w : expm1f(r.w);
    }
    ((float4*)agg)[gid] = r;
}

// ---------------- final layer (128 -> 10) ----------------

__global__ __launch_bounds__(256) void k_matmul_out(const float* __restrict__ H,
                                                    const float* __restrict__ W,
                                                    float* __restrict__ T2) {
    int gid = blockIdx.x * 256 + threadIdx.x;  // NN*16, cols padded to 16
    int row = gid >> 4, c = gid & 15;
    if (row >= NN || c >= NCLS) return;
    const float* h = H + (size_t)row * HID;
    float acc = 0.f;
#pragma unroll 8
    for (int k = 0; k < HID; ++k) acc += h[k] * W[k * NCLS + c];
    T2[row * NCLS + c] = acc;
}

__global__ __launch_bounds__(256) void k_scatter_out(const float* __restrict__ T2,
                                                     float* __restrict__ out,
                                                     const int* __restrict__ edge,
                                                     const float* __restrict__ norm) {
    int gid = blockIdx.x * 256 + threadIdx.x;  // NE*16
    int e = gid >> 4, c = gid & 15;
    if (e >= NE || c >= NCLS) return;
    int s = edge[e], d = edge[NE + e];
    atomicAdd(&out[d * NCLS + c], T2[s * NCLS + c] * norm[e]);
}

__global__ __launch_bounds__(256) void k_finalize_out(float* __restrict__ out,
                                                      const float* __restrict__ T2,
                                                      const float* __restrict__ dinv,
                                                      const float* __restrict__ bias) {
    int gid = blockIdx.x * 256 + threadIdx.x;  // NN*16
    int row = gid >> 4, c = gid & 15;
    if (row >= NN || c >= NCLS) return;
    float sn = dinv[row];
    sn *= sn;
    out[row * NCLS + c] += sn * T2[row * NCLS + c] + bias[c];
}

// ---------------- launch ----------------

extern "C" void kernel_launch(void* const* d_in, const int* in_sizes, int n_in,
                              void* d_out, int out_size, void* d_ws, size_t ws_size,
                              hipStream_t stream) {
    (void)in_sizes; (void)n_in; (void)out_size; (void)ws_size;
    const float* x       = (const float*)d_in[0];
    const int*   edge    = (const int*)d_in[1];   // [2, NE] int32; src = [0..NE), dst = [NE..2NE)
    const float* W_stack = (const float*)d_in[2]; // [8,128,128]
    const float* b_stack = (const float*)d_in[3]; // [8,128]
    const float* W_out   = (const float*)d_in[4]; // [128,10]
    const float* b_out   = (const float*)d_in[5]; // [10]
    float* out = (float*)d_out;

    char* ws = (char*)d_ws;
    const size_t bigbuf = (size_t)NN * HID * sizeof(float);  // 25.6 MB
    float* X    = (float*)ws;                 // H / agg buffer
    float* Y    = (float*)(ws + bigbuf);      // T buffer (also T2 for final layer)
    float* dinv = (float*)(ws + 2 * bigbuf);  // NN floats (deg computed in place)
    float* norm = dinv + NN;                  // NE floats

    const int NB_N = (NN + 255) / 256;        // 196
    const int NB_E = (NE + 255) / 256;        // 2344
    const int NB_MM = (NN + 31) / 32;         // 1563
    const int NB_SC = (NE * 32) / 256;        // 75000
    const int NB_FN = (NN * 32) / 256;        // 6250
    const int NB_O  = (NN * 16) / 256;        // 3125
    const int NB_SO = (NE * 16) / 256;        // 37500

    // graph prep (per call; same work every call)
    k_init_deg<<<NB_N, 256, 0, stream>>>(dinv);
    k_count_deg<<<NB_E, 256, 0, stream>>>(edge, dinv);
    k_dinv<<<NB_N, 256, 0, stream>>>(dinv);
    k_norm<<<NB_E, 256, 0, stream>>>(edge, dinv, norm);

    // 8 hidden layers
    const float* Hin = x;
    for (int l = 0; l < 8; ++l) {
        k_matmul128<<<NB_MM, 256, 0, stream>>>(Hin, W_stack + (size_t)l * HID * HID, Y);
        hipMemsetAsync(X, 0, bigbuf, stream);
        k_scatter128<<<NB_SC, 256, 0, stream>>>(Y, X, edge, norm);
        k_finalize128<<<NB_FN, 256, 0, stream>>>(X, Y, dinv, b_stack + (size_t)l * HID, 1);
        Hin = X;
    }

    // output layer (no activation)
    k_matmul_out<<<NB_O, 256, 0, stream>>>(X, W_out, Y);
    hipMemsetAsync(out, 0, (size_t)NN * NCLS * sizeof(float), stream);
    k_scatter_out<<<NB_SO, 256, 0, stream>>>(Y, out, edge, norm);
    k_finalize_out<<<NB_O, 256, 0, stream>>>(out, Y, dinv, b_out);
}

// Round 2
// 1088.812 us; speedup vs baseline: 8.1634x; 8.1634x over previous
//
#include <hip/hip_runtime.h>
#include <math.h>

#define NN 50000
#define NE 600000
#define HID 128
#define NCLS 10

// ================= graph prep: CSR by destination =================

__global__ __launch_bounds__(256) void k_count(const int* __restrict__ edge,
                                               int* __restrict__ counts) {
    int e = blockIdx.x * 256 + threadIdx.x;
    if (e < NE) atomicAdd(&counts[edge[NE + e]], 1);
}

__global__ __launch_bounds__(256) void k_dinv(const int* __restrict__ counts,
                                              float* __restrict__ dinv) {
    int i = blockIdx.x * 256 + threadIdx.x;
    if (i < NN) dinv[i] = rsqrtf((float)(counts[i] + 1));  // +1 self-loop
}

// single-block exclusive scan of counts[NN] -> rowptr[NN+1]
__global__ __launch_bounds__(1024) void k_scan(const int* __restrict__ counts,
                                               int* __restrict__ rowptr) {
    __shared__ int wsum[16];
    __shared__ int s_carry;
    int tid = threadIdx.x;
    int lane = tid & 63, wave = tid >> 6;
    if (tid == 0) s_carry = 0;
    __syncthreads();
    for (int base = 0; base < NN; base += 1024) {
        int i = base + tid;
        int v = (i < NN) ? counts[i] : 0;
        int x = v;
#pragma unroll
        for (int off = 1; off < 64; off <<= 1) {
            int y = __shfl_up(x, off, 64);
            if (lane >= off) x += y;
        }
        if (lane == 63) wsum[wave] = x;
        __syncthreads();
        if (wave == 0 && lane < 16) {
            int w = wsum[lane];
#pragma unroll
            for (int off = 1; off < 16; off <<= 1) {
                int y = __shfl_up(w, off, 64);
                if (lane >= off) w += y;
            }
            wsum[lane] = w;
        }
        __syncthreads();
        int c = s_carry;
        int excl = c + (wave ? wsum[wave - 1] : 0) + (x - v);
        if (i < NN) rowptr[i] = excl;
        __syncthreads();
        if (tid == 0) s_carry = c + wsum[15];
        __syncthreads();
    }
    if (tid == 0) rowptr[NN] = s_carry;  // == NE
}

__global__ __launch_bounds__(256) void k_fill(const int* __restrict__ edge,
                                              const int* __restrict__ rowptr,
                                              int* __restrict__ cursor,
                                              const float* __restrict__ dinv,
                                              int* __restrict__ csr_src,
                                              float* __restrict__ csr_norm) {
    int e = blockIdx.x * 256 + threadIdx.x;
    if (e >= NE) return;
    int s = edge[e], d = edge[NE + e];
    int p = rowptr[d] + atomicAdd(&cursor[d], 1);
    csr_src[p] = s;
    csr_norm[p] = dinv[s] * dinv[d];
}

// ================= dense: H[N,128] @ W[128,128] -> T =================

__device__ __forceinline__ float f4_get(const float4& v, int i) {
    return i == 0 ? v.x : i == 1 ? v.y : i == 2 ? v.z : v.w;
}

__global__ __launch_bounds__(256) void k_matmul128(const float* __restrict__ H,
                                                   const float* __restrict__ W,
                                                   float* __restrict__ T) {
    int tid = threadIdx.x;
    int cg  = tid & 31;
    int rg  = tid >> 5;
    int row0 = blockIdx.x * 32 + rg * 4;
    if (row0 >= NN) return;

    const float4* W4 = (const float4*)W;
    const float4* h0 = (const float4*)(H + (size_t)(row0 + 0) * HID);
    const float4* h1 = (const float4*)(H + (size_t)(row0 + 1) * HID);
    const float4* h2 = (const float4*)(H + (size_t)(row0 + 2) * HID);
    const float4* h3 = (const float4*)(H + (size_t)(row0 + 3) * HID);

    float4 acc0 = {0, 0, 0, 0}, acc1 = {0, 0, 0, 0}, acc2 = {0, 0, 0, 0}, acc3 = {0, 0, 0, 0};

#pragma unroll 8
    for (int k4 = 0; k4 < HID / 4; ++k4) {
        float4 a0 = h0[k4], a1 = h1[k4], a2 = h2[k4], a3 = h3[k4];
#pragma unroll
        for (int kk = 0; kk < 4; ++kk) {
            float4 w = W4[(size_t)(k4 * 4 + kk) * 32 + cg];
            float s0 = f4_get(a0, kk), s1 = f4_get(a1, kk);
            float s2 = f4_get(a2, kk), s3 = f4_get(a3, kk);
            acc0.x += s0 * w.x; acc0.y += s0 * w.y; acc0.z += s0 * w.z; acc0.w += s0 * w.w;
            acc1.x += s1 * w.x; acc1.y += s1 * w.y; acc1.z += s1 * w.z; acc1.w += s1 * w.w;
            acc2.x += s2 * w.x; acc2.y += s2 * w.y; acc2.z += s2 * w.z; acc2.w += s2 * w.w;
            acc3.x += s3 * w.x; acc3.y += s3 * w.y; acc3.z += s3 * w.z; acc3.w += s3 * w.w;
        }
    }
    ((float4*)(T + (size_t)(row0 + 0) * HID))[cg] = acc0;
    ((float4*)(T + (size_t)(row0 + 1) * HID))[cg] = acc1;
    ((float4*)(T + (size_t)(row0 + 2) * HID))[cg] = acc2;
    ((float4*)(T + (size_t)(row0 + 3) * HID))[cg] = acc3;
}

// ============ sparse by gather: one wave per node, fused epilogue ============
// lanes 0..31 handle edge i, lanes 32..63 edge i+1; each half-wave gathers the
// full 128-float row as float4 per lane. Combine halves with shfl, then
// self-loop + bias + ELU, single coalesced write.

__global__ __launch_bounds__(256) void k_gather_agg(const float* __restrict__ T,
                                                    float* __restrict__ Hout,
                                                    const int* __restrict__ rowptr,
                                                    const int* __restrict__ csr_src,
                                                    const float* __restrict__ csr_norm,
                                                    const float* __restrict__ dinv,
                                                    const float* __restrict__ bias) {
    int lane = threadIdx.x & 63;
    int node = (blockIdx.x * 256 + threadIdx.x) >> 6;
    if (node >= NN) return;
    int half = lane >> 5;  // edge slot 0/1
    int l32  = lane & 31;  // feature float4 index

    int beg = rowptr[node], end = rowptr[node + 1];
    float4 acc = {0.f, 0.f, 0.f, 0.f};
    for (int i = beg + half; i < end; i += 2) {
        int   s = csr_src[i];
        float w = csr_norm[i];
        float4 v = ((const float4*)(T + (size_t)s * HID))[l32];
        acc.x += w * v.x; acc.y += w * v.y; acc.z += w * v.z; acc.w += w * v.w;
    }
    acc.x += __shfl_xor(acc.x, 32, 64);
    acc.y += __shfl_xor(acc.y, 32, 64);
    acc.z += __shfl_xor(acc.z, 32, 64);
    acc.w += __shfl_xor(acc.w, 32, 64);

    if (half == 0) {
        float sn = dinv[node];
        sn *= sn;
        float4 t = ((const float4*)(T + (size_t)node * HID))[l32];
        float4 b = ((const float4*)bias)[l32];
        float4 r;
        r.x = acc.x + sn * t.x + b.x;
        r.y = acc.y + sn * t.y + b.y;
        r.z = acc.z + sn * t.z + b.z;
        r.w = acc.w + sn * t.w + b.w;
        r.x = r.x > 0.f ? r.x : expm1f(r.x);
        r.y = r.y > 0.f ? r.y : expm1f(r.y);
        r.z = r.z > 0.f ? r.z : expm1f(r.z);
        r.w = r.w > 0.f ? r.w : expm1f(r.w);
        ((float4*)(Hout + (size_t)node * HID))[l32] = r;
    }
}

// ================= output layer (128 -> 10) =================

__global__ __launch_bounds__(256) void k_matmul_out(const float* __restrict__ H,
                                                    const float* __restrict__ W,
                                                    float* __restrict__ T2) {
    int gid = blockIdx.x * 256 + threadIdx.x;  // NN*16 threads, cols padded to 16
    int row = gid >> 4, c = gid & 15;
    if (row >= NN || c >= NCLS) return;
    const float* h = H + (size_t)row * HID;
    float acc = 0.f;
#pragma unroll 8
    for (int k = 0; k < HID; ++k) acc += h[k] * W[k * NCLS + c];
    T2[row * NCLS + c] = acc;
}

// one wave per node; 4 edge slots x 16 lanes (10 cols active); no activation
__global__ __launch_bounds__(256) void k_gather_out(const float* __restrict__ T2,
                                                    float* __restrict__ out,
                                                    const int* __restrict__ rowptr,
                                                    const int* __restrict__ csr_src,
                                                    const float* __restrict__ csr_norm,
                                                    const float* __restrict__ dinv,
                                                    const float* __restrict__ bias) {
    int lane = threadIdx.x & 63;
    int node = (blockIdx.x * 256 + threadIdx.x) >> 6;
    if (node >= NN) return;
    int slot = lane >> 4, c = lane & 15;
    int beg = rowptr[node], end = rowptr[node + 1];
    float acc = 0.f;
    if (c < NCLS) {
        for (int i = beg + slot; i < end; i += 4) {
            acc += csr_norm[i] * T2[(size_t)csr_src[i] * NCLS + c];
        }
    }
    acc += __shfl_xor(acc, 16, 64);
    acc += __shfl_xor(acc, 32, 64);
    if (slot == 0 && c < NCLS) {
        float sn = dinv[node];
        sn *= sn;
        out[node * NCLS + c] = acc + sn * T2[(size_t)node * NCLS + c] + bias[c];
    }
}

// ================= launch =================

extern "C" void kernel_launch(void* const* d_in, const int* in_sizes, int n_in,
                              void* d_out, int out_size, void* d_ws, size_t ws_size,
                              hipStream_t stream) {
    (void)in_sizes; (void)n_in; (void)out_size; (void)ws_size;
    const float* x       = (const float*)d_in[0];
    const int*   edge    = (const int*)d_in[1];   // [2, NE] int32
    const float* W_stack = (const float*)d_in[2];
    const float* b_stack = (const float*)d_in[3];
    const float* W_out   = (const float*)d_in[4];
    const float* b_out   = (const float*)d_in[5];
    float* out = (float*)d_out;

    char* ws = (char*)d_ws;
    const size_t bigbuf = (size_t)NN * HID * sizeof(float);  // 25.6 MB
    float* X       = (float*)ws;
    float* Y       = (float*)(ws + bigbuf);
    char*  p       = ws + 2 * bigbuf;
    float* dinv    = (float*)p;             p += sizeof(float) * NN;
    int*   rowptr  = (int*)p;               p += sizeof(int) * (NN + 1);
    int*   counts  = (int*)p;               p += sizeof(int) * NN;      // later reused as cursor
    int*   csr_src = (int*)p;               p += sizeof(int) * NE;
    float* csr_nrm = (float*)p;             p += sizeof(float) * NE;

    const int NB_N  = (NN + 255) / 256;
    const int NB_E  = (NE + 255) / 256;
    const int NB_MM = (NN + 31) / 32;
    const int NB_W  = (NN * 64 + 255) / 256;   // one wave per node
    const int NB_O  = (NN * 16 + 255) / 256;

    // ---- CSR build (per call) ----
    hipMemsetAsync(counts, 0, sizeof(int) * NN, stream);
    k_count<<<NB_E, 256, 0, stream>>>(edge, counts);
    k_dinv<<<NB_N, 256, 0, stream>>>(counts, dinv);
    k_scan<<<1, 1024, 0, stream>>>(counts, rowptr);
    hipMemsetAsync(counts, 0, sizeof(int) * NN, stream);  // reuse as cursor
    k_fill<<<NB_E, 256, 0, stream>>>(edge, rowptr, counts, dinv, csr_src, csr_nrm);

    // ---- 8 hidden layers ----
    const float* Hin = x;
    for (int l = 0; l < 8; ++l) {
        k_matmul128<<<NB_MM, 256, 0, stream>>>(Hin, W_stack + (size_t)l * HID * HID, Y);
        k_gather_agg<<<NB_W, 256, 0, stream>>>(Y, X, rowptr, csr_src, csr_nrm, dinv,
                                               b_stack + (size_t)l * HID);
        Hin = X;
    }

    // ---- output layer ----
    k_matmul_out<<<NB_O, 256, 0, stream>>>(X, W_out, Y);
    k_gather_out<<<NB_W, 256, 0, stream>>>(Y, out, rowptr, csr_src, csr_nrm, dinv, b_out);
}

// Round 3
// 829.235 us; speedup vs baseline: 10.7188x; 1.3130x over previous
//
#include <hip/hip_runtime.h>
#include <math.h>

#define NN 50000
#define NE 600000
#define HID 128
#define NCLS 10
#define BK 16

// ================= graph prep: CSR by destination =================

__global__ __launch_bounds__(256) void k_count(const int* __restrict__ edge,
                                               int* __restrict__ counts) {
    int e = blockIdx.x * 256 + threadIdx.x;
    if (e < NE) atomicAdd(&counts[edge[NE + e]], 1);
}

__global__ __launch_bounds__(256) void k_dinv(const int* __restrict__ counts,
                                              float* __restrict__ dinv) {
    int i = blockIdx.x * 256 + threadIdx.x;
    if (i < NN) dinv[i] = rsqrtf((float)(counts[i] + 1));  // +1 self-loop
}

__device__ __forceinline__ int wave_incl_scan(int x, int lane) {
#pragma unroll
    for (int off = 1; off < 64; off <<= 1) {
        int y = __shfl_up(x, off, 64);
        if (lane >= off) x += y;
    }
    return x;
}

// phase 1: per-block exclusive scan of counts -> rowptr (block-local), block sums -> bsum
__global__ __launch_bounds__(256) void k_scan1(const int* __restrict__ counts,
                                               int* __restrict__ rowptr,
                                               int* __restrict__ bsum) {
    __shared__ int ws[4];
    int tid = threadIdx.x;
    int i = blockIdx.x * 256 + tid;
    int lane = tid & 63, wv = tid >> 6;
    int v = (i < NN) ? counts[i] : 0;
    int x = wave_incl_scan(v, lane);
    if (lane == 63) ws[wv] = x;
    __syncthreads();
    int off = 0;
    for (int j = 0; j < wv; ++j) off += ws[j];
    if (i < NN) rowptr[i] = off + x - v;
    if (tid == 255) bsum[blockIdx.x] = off + x;
}

// phase 2: single block, in-place exclusive scan of bsum[n] (n <= 256)
__global__ __launch_bounds__(256) void k_scan2(int* __restrict__ bsum, int n) {
    __shared__ int ws[4];
    int tid = threadIdx.x;
    int lane = tid & 63, wv = tid >> 6;
    int v = (tid < n) ? bsum[tid] : 0;
    int x = wave_incl_scan(v, lane);
    if (lane == 63) ws[wv] = x;
    __syncthreads();
    int off = 0;
    for (int j = 0; j < wv; ++j) off += ws[j];
    __syncthreads();
    if (tid < n) bsum[tid] = off + x - v;
}

// phase 3: add block offsets
__global__ __launch_bounds__(256) void k_scan3(int* __restrict__ rowptr,
                                               const int* __restrict__ bsum) {
    int i = blockIdx.x * 256 + threadIdx.x;
    if (i < NN) rowptr[i] += bsum[blockIdx.x];
    if (i == 0) rowptr[NN] = NE;
}

__global__ __launch_bounds__(256) void k_fill(const int* __restrict__ edge,
                                              const int* __restrict__ rowptr,
                                              int* __restrict__ cursor,
                                              const float* __restrict__ dinv,
                                              int* __restrict__ csr_src,
                                              float* __restrict__ csr_norm) {
    int e = blockIdx.x * 256 + threadIdx.x;
    if (e >= NE) return;
    int s = edge[e], d = edge[NE + e];
    int p = rowptr[d] + atomicAdd(&cursor[d], 1);
    csr_src[p] = s;
    csr_norm[p] = dinv[s] * dinv[d];
}

// ========== dense: H[N,128] @ W[128,128] -> T, 128x128 tile SGEMM ==========
// 256 thr = 4 waves (2x2); wave = 8x8 lanes; thread = 8 rows x 8 cols.
// As k-major [BK][128] so compute reads are ds_read_b128, <=2-way banked.

__global__ __launch_bounds__(256) void k_matmul128(const float* __restrict__ H,
                                                   const float* __restrict__ W,
                                                   float* __restrict__ T) {
    __shared__ float As[BK * 128];
    __shared__ float Bs[BK * 128];
    int tid = threadIdx.x;
    int lane = tid & 63, w = tid >> 6;
    int wr = lane >> 3, wc = lane & 7;
    int wy = w >> 1, wx = w & 1;
    int lr0 = wy * 64 + wr * 8;  // local row base
    int lc0 = wx * 64 + wc * 8;  // local col base
    int rowBase = blockIdx.x * 128;

    int sa_row = tid >> 1;            // 0..127
    int sa_k = (tid & 1) * 8;         // 0 or 8
    int sa_grow = rowBase + sa_row;
    if (sa_grow >= NN) sa_grow = NN - 1;

    float acc[8][8];
#pragma unroll
    for (int i = 0; i < 8; ++i)
#pragma unroll
        for (int j = 0; j < 8; ++j) acc[i][j] = 0.f;

    for (int k0 = 0; k0 < HID; k0 += BK) {
        const float* hsrc = H + (size_t)sa_grow * HID + k0 + sa_k;
        float4 a0 = ((const float4*)hsrc)[0];
        float4 a1 = ((const float4*)hsrc)[1];
        const float4* wsrc = (const float4*)(W + (size_t)k0 * HID);
        float4 b0 = wsrc[tid];
        float4 b1 = wsrc[tid + 256];
        __syncthreads();  // previous iter's LDS reads done
        As[(sa_k + 0) * 128 + sa_row] = a0.x;
        As[(sa_k + 1) * 128 + sa_row] = a0.y;
        As[(sa_k + 2) * 128 + sa_row] = a0.z;
        As[(sa_k + 3) * 128 + sa_row] = a0.w;
        As[(sa_k + 4) * 128 + sa_row] = a1.x;
        As[(sa_k + 5) * 128 + sa_row] = a1.y;
        As[(sa_k + 6) * 128 + sa_row] = a1.z;
        As[(sa_k + 7) * 128 + sa_row] = a1.w;
        ((float4*)Bs)[tid] = b0;
        ((float4*)Bs)[tid + 256] = b1;
        __syncthreads();
#pragma unroll
        for (int kk = 0; kk < BK; ++kk) {
            float a[8], b[8];
            ((float4*)a)[0] = *(const float4*)&As[kk * 128 + lr0];
            ((float4*)a)[1] = *(const float4*)&As[kk * 128 + lr0 + 4];
            ((float4*)b)[0] = *(const float4*)&Bs[kk * 128 + lc0];
            ((float4*)b)[1] = *(const float4*)&Bs[kk * 128 + lc0 + 4];
#pragma unroll
            for (int i = 0; i < 8; ++i)
#pragma unroll
                for (int j = 0; j < 8; ++j) acc[i][j] += a[i] * b[j];
        }
    }
#pragma unroll
    for (int i = 0; i < 8; ++i) {
        int gr = rowBase + lr0 + i;
        if (gr < NN) {
            float4 o0 = {acc[i][0], acc[i][1], acc[i][2], acc[i][3]};
            float4 o1 = {acc[i][4], acc[i][5], acc[i][6], acc[i][7]};
            float4* dst = (float4*)(T + (size_t)gr * HID + lc0);
            dst[0] = o0;
            dst[1] = o1;
        }
    }
}

// ============ sparse by gather: one wave per node, fused epilogue ============
// 4 edge slots x 16 lanes; each lane handles 8 floats (2 float4) of the row.

__global__ __launch_bounds__(256) void k_gather_agg(const float* __restrict__ T,
                                                    float* __restrict__ Hout,
                                                    const int* __restrict__ rowptr,
                                                    const int* __restrict__ csr_src,
                                                    const float* __restrict__ csr_norm,
                                                    const float* __restrict__ dinv,
                                                    const float* __restrict__ bias) {
    int lane = threadIdx.x & 63;
    int node = (blockIdx.x * 256 + threadIdx.x) >> 6;
    if (node >= NN) return;
    int slot = lane >> 4, c16 = lane & 15;

    int beg = rowptr[node], end = rowptr[node + 1];
    float4 acc0 = {0.f, 0.f, 0.f, 0.f}, acc1 = {0.f, 0.f, 0.f, 0.f};
    for (int i = beg + slot; i < end; i += 4) {
        int s = csr_src[i];
        float wgt = csr_norm[i];
        const float4* src = (const float4*)(T + (size_t)s * HID) + c16 * 2;
        float4 v0 = src[0], v1 = src[1];
        acc0.x += wgt * v0.x; acc0.y += wgt * v0.y; acc0.z += wgt * v0.z; acc0.w += wgt * v0.w;
        acc1.x += wgt * v1.x; acc1.y += wgt * v1.y; acc1.z += wgt * v1.z; acc1.w += wgt * v1.w;
    }
    acc0.x += __shfl_xor(acc0.x, 16, 64); acc0.y += __shfl_xor(acc0.y, 16, 64);
    acc0.z += __shfl_xor(acc0.z, 16, 64); acc0.w += __shfl_xor(acc0.w, 16, 64);
    acc1.x += __shfl_xor(acc1.x, 16, 64); acc1.y += __shfl_xor(acc1.y, 16, 64);
    acc1.z += __shfl_xor(acc1.z, 16, 64); acc1.w += __shfl_xor(acc1.w, 16, 64);
    acc0.x += __shfl_xor(acc0.x, 32, 64); acc0.y += __shfl_xor(acc0.y, 32, 64);
    acc0.z += __shfl_xor(acc0.z, 32, 64); acc0.w += __shfl_xor(acc0.w, 32, 64);
    acc1.x += __shfl_xor(acc1.x, 32, 64); acc1.y += __shfl_xor(acc1.y, 32, 64);
    acc1.z += __shfl_xor(acc1.z, 32, 64); acc1.w += __shfl_xor(acc1.w, 32, 64);

    if (slot == 0) {
        float sn = dinv[node];
        sn *= sn;
        const float4* trow = (const float4*)(T + (size_t)node * HID) + c16 * 2;
        float4 t0 = trow[0], t1 = trow[1];
        const float4* b4 = (const float4*)bias + c16 * 2;
        float4 b0 = b4[0], b1 = b4[1];
        float4 r0, r1;
        r0.x = acc0.x + sn * t0.x + b0.x; r0.y = acc0.y + sn * t0.y + b0.y;
        r0.z = acc0.z + sn * t0.z + b0.z; r0.w = acc0.w + sn * t0.w + b0.w;
        r1.x = acc1.x + sn * t1.x + b1.x; r1.y = acc1.y + sn * t1.y + b1.y;
        r1.z = acc1.z + sn * t1.z + b1.z; r1.w = acc1.w + sn * t1.w + b1.w;
        r0.x = r0.x > 0.f ? r0.x : expm1f(r0.x);
        r0.y = r0.y > 0.f ? r0.y : expm1f(r0.y);
        r0.z = r0.z > 0.f ? r0.z : expm1f(r0.z);
        r0.w = r0.w > 0.f ? r0.w : expm1f(r0.w);
        r1.x = r1.x > 0.f ? r1.x : expm1f(r1.x);
        r1.y = r1.y > 0.f ? r1.y : expm1f(r1.y);
        r1.z = r1.z > 0.f ? r1.z : expm1f(r1.z);
        r1.w = r1.w > 0.f ? r1.w : expm1f(r1.w);
        float4* dst = (float4*)(Hout + (size_t)node * HID) + c16 * 2;
        dst[0] = r0;
        dst[1] = r1;
    }
}

// ================= output layer (128 -> 10) =================

__global__ __launch_bounds__(256) void k_matmul_out(const float* __restrict__ H,
                                                    const float* __restrict__ W,
                                                    float* __restrict__ T2) {
    int gid = blockIdx.x * 256 + threadIdx.x;  // NN*16 threads, cols padded to 16
    int row = gid >> 4, c = gid & 15;
    if (row >= NN || c >= NCLS) return;
    const float* h = H + (size_t)row * HID;
    float acc = 0.f;
#pragma unroll 8
    for (int k = 0; k < HID; ++k) acc += h[k] * W[k * NCLS + c];
    T2[row * NCLS + c] = acc;
}

__global__ __launch_bounds__(256) void k_gather_out(const float* __restrict__ T2,
                                                    float* __restrict__ out,
                                                    const int* __restrict__ rowptr,
                                                    const int* __restrict__ csr_src,
                                                    const float* __restrict__ csr_norm,
                                                    const float* __restrict__ dinv,
                                                    const float* __restrict__ bias) {
    int lane = threadIdx.x & 63;
    int node = (blockIdx.x * 256 + threadIdx.x) >> 6;
    if (node >= NN) return;
    int slot = lane >> 4, c = lane & 15;
    int beg = rowptr[node], end = rowptr[node + 1];
    float acc = 0.f;
    if (c < NCLS) {
        for (int i = beg + slot; i < end; i += 4) {
            acc += csr_norm[i] * T2[(size_t)csr_src[i] * NCLS + c];
        }
    }
    acc += __shfl_xor(acc, 16, 64);
    acc += __shfl_xor(acc, 32, 64);
    if (slot == 0 && c < NCLS) {
        float sn = dinv[node];
        sn *= sn;
        out[node * NCLS + c] = acc + sn * T2[(size_t)node * NCLS + c] + bias[c];
    }
}

// ================= launch =================

extern "C" void kernel_launch(void* const* d_in, const int* in_sizes, int n_in,
                              void* d_out, int out_size, void* d_ws, size_t ws_size,
                              hipStream_t stream) {
    (void)in_sizes; (void)n_in; (void)out_size; (void)ws_size;
    const float* x       = (const float*)d_in[0];
    const int*   edge    = (const int*)d_in[1];   // [2, NE] int32
    const float* W_stack = (const float*)d_in[2];
    const float* b_stack = (const float*)d_in[3];
    const float* W_out   = (const float*)d_in[4];
    const float* b_out   = (const float*)d_in[5];
    float* out = (float*)d_out;

    char* ws = (char*)d_ws;
    const size_t bigbuf = (size_t)NN * HID * sizeof(float);  // 25.6 MB
    float* X       = (float*)ws;
    float* Y       = (float*)(ws + bigbuf);
    char*  p       = ws + 2 * bigbuf;
    float* dinv    = (float*)p;             p += sizeof(float) * NN;
    int*   rowptr  = (int*)p;               p += sizeof(int) * (NN + 1);
    int*   counts  = (int*)p;               p += sizeof(int) * NN;      // reused as cursor
    int*   bsum    = (int*)p;               p += sizeof(int) * 256;
    int*   csr_src = (int*)p;               p += sizeof(int) * NE;
    float* csr_nrm = (float*)p;             p += sizeof(float) * NE;

    const int NB_N  = (NN + 255) / 256;        // 196
    const int NB_E  = (NE + 255) / 256;
    const int NB_MM = (NN + 127) / 128;        // 391
    const int NB_W  = (NN * 64 + 255) / 256;   // one wave per node
    const int NB_O  = (NN * 16 + 255) / 256;

    // ---- CSR build (per call) ----
    hipMemsetAsync(counts, 0, sizeof(int) * NN, stream);
    k_count<<<NB_E, 256, 0, stream>>>(edge, counts);
    k_dinv<<<NB_N, 256, 0, stream>>>(counts, dinv);
    k_scan1<<<NB_N, 256, 0, stream>>>(counts, rowptr, bsum);
    k_scan2<<<1, 256, 0, stream>>>(bsum, NB_N);
    k_scan3<<<NB_N, 256, 0, stream>>>(rowptr, bsum);
    hipMemsetAsync(counts, 0, sizeof(int) * NN, stream);  // reuse as cursor
    k_fill<<<NB_E, 256, 0, stream>>>(edge, rowptr, counts, dinv, csr_src, csr_nrm);

    // ---- 8 hidden layers ----
    const float* Hin = x;
    for (int l = 0; l < 8; ++l) {
        k_matmul128<<<NB_MM, 256, 0, stream>>>(Hin, W_stack + (size_t)l * HID * HID, Y);
        k_gather_agg<<<NB_W, 256, 0, stream>>>(Y, X, rowptr, csr_src, csr_nrm, dinv,
                                               b_stack + (size_t)l * HID);
        Hin = X;
    }

    // ---- output layer ----
    k_matmul_out<<<NB_O, 256, 0, stream>>>(X, W_out, Y);
    k_gather_out<<<NB_W, 256, 0, stream>>>(Y, out, rowptr, csr_src, csr_nrm, dinv, b_out);
}

// Round 4
// 810.081 us; speedup vs baseline: 10.9723x; 1.0236x over previous
//
#include <hip/hip_runtime.h>
#include <math.h>

#define NN 50000
#define NE 600000
#define HID 128
#define NCLS 10
#define BK 32

// ================= graph prep: CSR by destination =================

__global__ __launch_bounds__(256) void k_count(const int* __restrict__ edge,
                                               int* __restrict__ counts) {
    int e = blockIdx.x * 256 + threadIdx.x;
    if (e < NE) atomicAdd(&counts[edge[NE + e]], 1);
}

__device__ __forceinline__ int wave_incl_scan(int x, int lane) {
#pragma unroll
    for (int off = 1; off < 64; off <<= 1) {
        int y = __shfl_up(x, off, 64);
        if (lane >= off) x += y;
    }
    return x;
}

// per-block exclusive scan of counts -> rowptr (block-local), block sums -> bsum
// fused: dinv[i] = rsqrt(counts[i]+1)
__global__ __launch_bounds__(256) void k_scan1(const int* __restrict__ counts,
                                               int* __restrict__ rowptr,
                                               int* __restrict__ bsum,
                                               float* __restrict__ dinv) {
    __shared__ int ws[4];
    int tid = threadIdx.x;
    int i = blockIdx.x * 256 + tid;
    int lane = tid & 63, wv = tid >> 6;
    int v = (i < NN) ? counts[i] : 0;
    if (i < NN) dinv[i] = rsqrtf((float)(v + 1));
    int x = wave_incl_scan(v, lane);
    if (lane == 63) ws[wv] = x;
    __syncthreads();
    int off = 0;
    for (int j = 0; j < wv; ++j) off += ws[j];
    if (i < NN) rowptr[i] = off + x - v;
    if (tid == 255) bsum[blockIdx.x] = off + x;
}

__global__ __launch_bounds__(256) void k_scan2(int* __restrict__ bsum, int n) {
    __shared__ int ws[4];
    int tid = threadIdx.x;
    int lane = tid & 63, wv = tid >> 6;
    int v = (tid < n) ? bsum[tid] : 0;
    int x = wave_incl_scan(v, lane);
    if (lane == 63) ws[wv] = x;
    __syncthreads();
    int off = 0;
    for (int j = 0; j < wv; ++j) off += ws[j];
    __syncthreads();
    if (tid < n) bsum[tid] = off + x - v;
}

__global__ __launch_bounds__(256) void k_scan3(int* __restrict__ rowptr,
                                               const int* __restrict__ bsum) {
    int i = blockIdx.x * 256 + threadIdx.x;
    if (i < NN) rowptr[i] += bsum[blockIdx.x];
    if (i == 0) rowptr[NN] = NE;
}

__global__ __launch_bounds__(256) void k_fill(const int* __restrict__ edge,
                                              const int* __restrict__ rowptr,
                                              int* __restrict__ cursor,
                                              const float* __restrict__ dinv,
                                              int2* __restrict__ csr) {
    int e = blockIdx.x * 256 + threadIdx.x;
    if (e >= NE) return;
    int s = edge[e], d = edge[NE + e];
    int p = rowptr[d] + atomicAdd(&cursor[d], 1);
    csr[p] = make_int2(s, __float_as_int(dinv[s] * dinv[d]));
}

// ========== dense: H[N,128] @ W[128,128] -> T, 128x128 tile SGEMM ==========
// 256 thr = 4 waves (2x2); wave = 8x8 lanes; thread = 8 rows x 8 cols; BK=32.

__global__ __launch_bounds__(256) void k_matmul128(const float* __restrict__ H,
                                                   const float* __restrict__ W,
                                                   float* __restrict__ T) {
    __shared__ float As[BK * 128];  // k-major [k][row], 16 KB
    __shared__ float Bs[BK * 128];  // [k][col], 16 KB
    int tid = threadIdx.x;
    int lane = tid & 63, w = tid >> 6;
    int wr = lane >> 3, wc = lane & 7;
    int wy = w >> 1, wx = w & 1;
    int lr0 = wy * 64 + wr * 8;
    int lc0 = wx * 64 + wc * 8;
    int rowBase = blockIdx.x * 128;

    int sa_row = tid >> 1;            // 0..127
    int sa_k = (tid & 1) * 16;        // 0 or 16
    int sa_grow = rowBase + sa_row;
    if (sa_grow >= NN) sa_grow = NN - 1;

    float acc[8][8];
#pragma unroll
    for (int i = 0; i < 8; ++i)
#pragma unroll
        for (int j = 0; j < 8; ++j) acc[i][j] = 0.f;

    for (int k0 = 0; k0 < HID; k0 += BK) {
        const float4* hsrc = (const float4*)(H + (size_t)sa_grow * HID + k0 + sa_k);
        float4 a0 = hsrc[0], a1 = hsrc[1], a2 = hsrc[2], a3 = hsrc[3];
        const float4* wsrc = (const float4*)(W + (size_t)k0 * HID);
        float4 b0 = wsrc[tid], b1 = wsrc[tid + 256], b2 = wsrc[tid + 512], b3 = wsrc[tid + 768];
        __syncthreads();  // previous iter's LDS reads done
        As[(sa_k + 0) * 128 + sa_row] = a0.x;  As[(sa_k + 1) * 128 + sa_row] = a0.y;
        As[(sa_k + 2) * 128 + sa_row] = a0.z;  As[(sa_k + 3) * 128 + sa_row] = a0.w;
        As[(sa_k + 4) * 128 + sa_row] = a1.x;  As[(sa_k + 5) * 128 + sa_row] = a1.y;
        As[(sa_k + 6) * 128 + sa_row] = a1.z;  As[(sa_k + 7) * 128 + sa_row] = a1.w;
        As[(sa_k + 8) * 128 + sa_row] = a2.x;  As[(sa_k + 9) * 128 + sa_row] = a2.y;
        As[(sa_k + 10) * 128 + sa_row] = a2.z; As[(sa_k + 11) * 128 + sa_row] = a2.w;
        As[(sa_k + 12) * 128 + sa_row] = a3.x; As[(sa_k + 13) * 128 + sa_row] = a3.y;
        As[(sa_k + 14) * 128 + sa_row] = a3.z; As[(sa_k + 15) * 128 + sa_row] = a3.w;
        ((float4*)Bs)[tid] = b0;
        ((float4*)Bs)[tid + 256] = b1;
        ((float4*)Bs)[tid + 512] = b2;
        ((float4*)Bs)[tid + 768] = b3;
        __syncthreads();
#pragma unroll
        for (int kk = 0; kk < BK; ++kk) {
            float a[8], b[8];
            ((float4*)a)[0] = *(const float4*)&As[kk * 128 + lr0];
            ((float4*)a)[1] = *(const float4*)&As[kk * 128 + lr0 + 4];
            ((float4*)b)[0] = *(const float4*)&Bs[kk * 128 + lc0];
            ((float4*)b)[1] = *(const float4*)&Bs[kk * 128 + lc0 + 4];
#pragma unroll
            for (int i = 0; i < 8; ++i)
#pragma unroll
                for (int j = 0; j < 8; ++j) acc[i][j] += a[i] * b[j];
        }
    }
#pragma unroll
    for (int i = 0; i < 8; ++i) {
        int gr = rowBase + lr0 + i;
        if (gr < NN) {
            float4 o0 = {acc[i][0], acc[i][1], acc[i][2], acc[i][3]};
            float4 o1 = {acc[i][4], acc[i][5], acc[i][6], acc[i][7]};
            float4* dst = (float4*)(T + (size_t)gr * HID + lc0);
            dst[0] = o0;
            dst[1] = o1;
        }
    }
}

// ============ sparse by gather: one wave per node, pipelined, fused epilogue ============
// 4 edge slots x 16 lanes; lane covers 8 floats (2 float4). 2-edge unroll +
// one-ahead csr prefetch -> 4 independent row loads in flight per lane.

__global__ __launch_bounds__(256) void k_gather_agg(const float* __restrict__ T,
                                                    float* __restrict__ Hout,
                                                    const int* __restrict__ rowptr,
                                                    const int2* __restrict__ csr,
                                                    const float* __restrict__ dinv,
                                                    const float* __restrict__ bias) {
    int lane = threadIdx.x & 63;
    int node = (blockIdx.x * 256 + threadIdx.x) >> 6;
    if (node >= NN) return;
    int slot = lane >> 4, c16 = lane & 15;

    int beg = rowptr[node], end = rowptr[node + 1];
    float4 acc0 = {0.f, 0.f, 0.f, 0.f}, acc1 = {0.f, 0.f, 0.f, 0.f};
    const int2 zed = make_int2(0, 0);  // norm bits 0 -> weight 0

    int i = beg + slot;
    int2 e0 = (i < end) ? csr[i] : zed;
    int2 e1 = (i + 4 < end) ? csr[i + 4] : zed;
    for (; i < end; i += 8) {
        int2 p0 = (i + 8 < end) ? csr[i + 8] : zed;
        int2 p1 = (i + 12 < end) ? csr[i + 12] : zed;
        const float4* s0 = (const float4*)(T + (size_t)e0.x * HID) + c16 * 2;
        const float4* s1 = (const float4*)(T + (size_t)e1.x * HID) + c16 * 2;
        float4 u0 = s0[0], u1 = s0[1];
        float4 v0 = s1[0], v1 = s1[1];
        float w0 = __int_as_float(e0.y);
        float w1 = __int_as_float(e1.y);
        acc0.x += w0 * u0.x; acc0.y += w0 * u0.y; acc0.z += w0 * u0.z; acc0.w += w0 * u0.w;
        acc1.x += w0 * u1.x; acc1.y += w0 * u1.y; acc1.z += w0 * u1.z; acc1.w += w0 * u1.w;
        acc0.x += w1 * v0.x; acc0.y += w1 * v0.y; acc0.z += w1 * v0.z; acc0.w += w1 * v0.w;
        acc1.x += w1 * v1.x; acc1.y += w1 * v1.y; acc1.z += w1 * v1.z; acc1.w += w1 * v1.w;
        e0 = p0; e1 = p1;
    }
    acc0.x += __shfl_xor(acc0.x, 16, 64); acc0.y += __shfl_xor(acc0.y, 16, 64);
    acc0.z += __shfl_xor(acc0.z, 16, 64); acc0.w += __shfl_xor(acc0.w, 16, 64);
    acc1.x += __shfl_xor(acc1.x, 16, 64); acc1.y += __shfl_xor(acc1.y, 16, 64);
    acc1.z += __shfl_xor(acc1.z, 16, 64); acc1.w += __shfl_xor(acc1.w, 16, 64);
    acc0.x += __shfl_xor(acc0.x, 32, 64); acc0.y += __shfl_xor(acc0.y, 32, 64);
    acc0.z += __shfl_xor(acc0.z, 32, 64); acc0.w += __shfl_xor(acc0.w, 32, 64);
    acc1.x += __shfl_xor(acc1.x, 32, 64); acc1.y += __shfl_xor(acc1.y, 32, 64);
    acc1.z += __shfl_xor(acc1.z, 32, 64); acc1.w += __shfl_xor(acc1.w, 32, 64);

    if (slot == 0) {
        float sn = dinv[node];
        sn *= sn;
        const float4* trow = (const float4*)(T + (size_t)node * HID) + c16 * 2;
        float4 t0 = trow[0], t1 = trow[1];
        const float4* b4 = (const float4*)bias + c16 * 2;
        float4 b0 = b4[0], b1 = b4[1];
        float4 r0, r1;
        r0.x = acc0.x + sn * t0.x + b0.x; r0.y = acc0.y + sn * t0.y + b0.y;
        r0.z = acc0.z + sn * t0.z + b0.z; r0.w = acc0.w + sn * t0.w + b0.w;
        r1.x = acc1.x + sn * t1.x + b1.x; r1.y = acc1.y + sn * t1.y + b1.y;
        r1.z = acc1.z + sn * t1.z + b1.z; r1.w = acc1.w + sn * t1.w + b1.w;
        r0.x = r0.x > 0.f ? r0.x : expm1f(r0.x);
        r0.y = r0.y > 0.f ? r0.y : expm1f(r0.y);
        r0.z = r0.z > 0.f ? r0.z : expm1f(r0.z);
        r0.w = r0.w > 0.f ? r0.w : expm1f(r0.w);
        r1.x = r1.x > 0.f ? r1.x : expm1f(r1.x);
        r1.y = r1.y > 0.f ? r1.y : expm1f(r1.y);
        r1.z = r1.z > 0.f ? r1.z : expm1f(r1.z);
        r1.w = r1.w > 0.f ? r1.w : expm1f(r1.w);
        float4* dst = (float4*)(Hout + (size_t)node * HID) + c16 * 2;
        dst[0] = r0;
        dst[1] = r1;
    }
}

// ================= output layer (128 -> 10) =================
// wave = 4 rows x 16 lanes; lane handles k = c16 + 16j; W staged in LDS, pad 11.

__global__ __launch_bounds__(256) void k_matmul_out(const float* __restrict__ H,
                                                    const float* __restrict__ W,
                                                    float* __restrict__ T2) {
    __shared__ float Ws[128 * 11];
    int tid = threadIdx.x;
    for (int m = tid; m < HID * NCLS; m += 256) {
        int k = m / NCLS, c = m - k * NCLS;
        Ws[k * 11 + c] = W[m];
    }
    __syncthreads();
    int row = (blockIdx.x * 256 + tid) >> 4;
    int c16 = tid & 15;
    if (row >= NN) return;
    const float* h = H + (size_t)row * HID;
    float acc[NCLS];
#pragma unroll
    for (int c = 0; c < NCLS; ++c) acc[c] = 0.f;
#pragma unroll
    for (int j = 0; j < 8; ++j) {
        float hv = h[c16 + 16 * j];
        const float* wr = &Ws[(c16 + 16 * j) * 11];
#pragma unroll
        for (int c = 0; c < NCLS; ++c) acc[c] += hv * wr[c];
    }
#pragma unroll
    for (int off = 8; off >= 1; off >>= 1) {
#pragma unroll
        for (int c = 0; c < NCLS; ++c) acc[c] += __shfl_xor(acc[c], off, 16);
    }
    if (c16 < NCLS) T2[(size_t)row * NCLS + c16] = acc[c16];
}

__global__ __launch_bounds__(256) void k_gather_out(const float* __restrict__ T2,
                                                    float* __restrict__ out,
                                                    const int* __restrict__ rowptr,
                                                    const int2* __restrict__ csr,
                                                    const float* __restrict__ dinv,
                                                    const float* __restrict__ bias) {
    int lane = threadIdx.x & 63;
    int node = (blockIdx.x * 256 + threadIdx.x) >> 6;
    if (node >= NN) return;
    int slot = lane >> 4, c = lane & 15;
    int beg = rowptr[node], end = rowptr[node + 1];
    float acc = 0.f;
    if (c < NCLS) {
        for (int i = beg + slot; i < end; i += 4) {
            int2 e = csr[i];
            acc += __int_as_float(e.y) * T2[(size_t)e.x * NCLS + c];
        }
    }
    acc += __shfl_xor(acc, 16, 64);
    acc += __shfl_xor(acc, 32, 64);
    if (slot == 0 && c < NCLS) {
        float sn = dinv[node];
        sn *= sn;
        out[node * NCLS + c] = acc + sn * T2[(size_t)node * NCLS + c] + bias[c];
    }
}

// ================= launch =================

extern "C" void kernel_launch(void* const* d_in, const int* in_sizes, int n_in,
                              void* d_out, int out_size, void* d_ws, size_t ws_size,
                              hipStream_t stream) {
    (void)in_sizes; (void)n_in; (void)out_size; (void)ws_size;
    const float* x       = (const float*)d_in[0];
    const int*   edge    = (const int*)d_in[1];   // [2, NE] int32
    const float* W_stack = (const float*)d_in[2];
    const float* b_stack = (const float*)d_in[3];
    const float* W_out   = (const float*)d_in[4];
    const float* b_out   = (const float*)d_in[5];
    float* out = (float*)d_out;

    char* ws = (char*)d_ws;
    const size_t bigbuf = (size_t)NN * HID * sizeof(float);  // 25.6 MB
    float* X      = (float*)ws;
    float* Y      = (float*)(ws + bigbuf);
    char*  p      = ws + 2 * bigbuf;
    int2*  csr    = (int2*)p;              p += sizeof(int2) * NE;   // 8-B aligned
    float* dinv   = (float*)p;             p += sizeof(float) * NN;
    int*   rowptr = (int*)p;               p += sizeof(int) * (NN + 1);
    int*   counts = (int*)p;               p += sizeof(int) * NN;    // reused as cursor
    int*   bsum   = (int*)p;               p += sizeof(int) * 256;

    const int NB_N  = (NN + 255) / 256;        // 196
    const int NB_E  = (NE + 255) / 256;
    const int NB_MM = (NN + 127) / 128;        // 391
    const int NB_W  = (NN * 64 + 255) / 256;   // one wave per node
    const int NB_O  = (NN * 16 + 255) / 256;

    // ---- CSR build (per call) ----
    hipMemsetAsync(counts, 0, sizeof(int) * NN, stream);
    k_count<<<NB_E, 256, 0, stream>>>(edge, counts);
    k_scan1<<<NB_N, 256, 0, stream>>>(counts, rowptr, bsum, dinv);
    k_scan2<<<1, 256, 0, stream>>>(bsum, NB_N);
    k_scan3<<<NB_N, 256, 0, stream>>>(rowptr, bsum);
    hipMemsetAsync(counts, 0, sizeof(int) * NN, stream);  // reuse as cursor
    k_fill<<<NB_E, 256, 0, stream>>>(edge, rowptr, counts, dinv, csr);

    // ---- 8 hidden layers ----
    const float* Hin = x;
    for (int l = 0; l < 8; ++l) {
        k_matmul128<<<NB_MM, 256, 0, stream>>>(Hin, W_stack + (size_t)l * HID * HID, Y);
        k_gather_agg<<<NB_W, 256, 0, stream>>>(Y, X, rowptr, csr, dinv,
                                               b_stack + (size_t)l * HID);
        Hin = X;
    }

    // ---- output layer ----
    k_matmul_out<<<NB_O, 256, 0, stream>>>(X, W_out, Y);
    k_gather_out<<<NB_W, 256, 0, stream>>>(Y, out, rowptr, csr, dinv, b_out);
}